// Round 6
// baseline (302.236 us; speedup 1.0000x reference)
//
#include <hip/hip_runtime.h>

// Problem constants (static per reference): x shape (B, C, H, W) fp32
#define B   64
#define C   2048
#define H   24
#define W   12
#define S   (H * W)        // 288 spatial positions per (b, c)
#define S4  (S / 4)        // 72 float4 per channel slice
#define W4  (W / 4)        // 3 float4 per row
#define NCH 32             // channel chunks
#define CCH (C / NCH)      // 64 channels per chunk
#define RH  8              // round(0.33 * 24)

// Native clang vector type — required by __builtin_nontemporal_store
// (HIP's float4 is a struct wrapper it rejects). Lowers to dwordx4 ops.
typedef float f4 __attribute__((ext_vector_type(4)));

// ---------------------------------------------------------------------------
// Round-6 restructure: COPY-THEN-PATCH. The old 2-pass form streamed x twice
// (energy pass + masked-copy pass); L3 only half-absorbed the second read
// (round-1 k2 FETCH=82 MB). The mask depends on the full reduction, but the
// COPY doesn't: so pass 1 copies x verbatim while accumulating energy
// (x read from HBM exactly once), and pass 2 only zero-patches the 8
// dropped rows per sample (50 MB of writes instead of a 302 MB re-stream).
// Copy stores are temporal: out lines stay dirty in L2/MALL so the patch
// mostly merges in-cache (old NT rationale — protecting x's L3 residency
// for a re-read — no longer applies; nothing re-reads x).
// ---------------------------------------------------------------------------

// ---------------------------------------------------------------------------
// Kernel 1: fused energy + verbatim copy. Block (chunk, b), 288 threads.
// Thread t, iteration k accesses float4 index t + 288k within the chunk's
// 4608-float4 span -> the block walks contiguous 4.6 KB spans, perfectly
// coalesced both directions. Thread t's 4 spatial positions are fixed
// (spatial f4 = t%72, channel = t/72 + 4k) -> register accumulate.
// Loads batched 8-deep (compiler alone pipelines only ~4-deep).
// ---------------------------------------------------------------------------
__global__ __launch_bounds__(288) void k_energy_copy(const float* __restrict__ x,
                                                     float* __restrict__ out,
                                                     float* __restrict__ part) {
    const int chunk = blockIdx.x;   // 0..NCH-1
    const int b     = blockIdx.y;   // 0..B-1
    const int t     = threadIdx.x;  // 0..287
    const int f     = t % S4;
    const int g     = t / S4;

    const size_t base4 = (size_t)(b * C + chunk * CCH) * S4;
    const f4* __restrict__ x4 = (const f4*)x + base4;
    f4* __restrict__       o4 = (f4*)out + base4;

    f4 acc = {0.f, 0.f, 0.f, 0.f};
    #pragma unroll
    for (int kk = 0; kk < 2; ++kk) {
        f4 v[8];
        #pragma unroll
        for (int j = 0; j < 8; ++j) v[j] = x4[t + S * (kk * 8 + j)];
        #pragma unroll
        for (int j = 0; j < 8; ++j) {
            o4[t + S * (kk * 8 + j)] = v[j];   // bit-exact copy
            acc += v[j] * v[j];
        }
    }

    __shared__ f4 sm4[4][S4];   // 4.6 KB
    sm4[g][f] = acc;
    __syncthreads();

    const float* sm = (const float*)sm4;
    // thread t owns spatial position t (t < 288 == S)
    part[((size_t)b * NCH + chunk) * S + t] =
        sm[0 * S + t] + sm[1 * S + t] + sm[2 * S + t] + sm[3 * S + t];
}

// ---------------------------------------------------------------------------
// Kernel 2: fused select + zero-patch. Block (chunk, b), 288 threads.
// Each block redundantly reduces its sample's 32x288 partials (36 KB,
// L2/MALL-resident -> ~free, proven in rounds 1-5), ranks rows, compacts
// the RH dropped row indices, then zeroes those rows in its chunk:
// 64 channels x 8 rows x 3 f4 = 1536 stores (24 KB/block, 50 MB total).
//
// Tie semantics match stable argsort(ascending)[-RH:]: on equal values the
// larger index wins a top (dropped) slot. cnt (# rows strictly above row t
// in (value,index) order) < RH  <=>  dropped; cnt is also a unique slot in
// [0,RH) -> race-free compaction without atomics.
//
// The patch writes are inherently 48 B-granular (that IS the write set);
// lanes 3j..3j+2 write one contiguous 48 B row segment. Most patched lines
// are still dirty in cache from k1's copy -> merge before HBM.
// ---------------------------------------------------------------------------
__global__ __launch_bounds__(288) void k_select_zero(const float* __restrict__ part,
                                                     float* __restrict__ out) {
    const int chunk = blockIdx.x;   // 0..NCH-1
    const int b     = blockIdx.y;
    const int t     = threadIdx.x;  // 0..287

    __shared__ float act[S];
    __shared__ float rm[H];
    __shared__ int   dIdx[RH];

    // 1. reduce the 32 chunk partials -> act[288] (coalesced across t)
    {
        const float* p = part + (size_t)b * NCH * S + t;
        float sum = 0.f;
        #pragma unroll
        for (int ch = 0; ch < NCH; ch++) sum += p[(size_t)ch * S];
        act[t] = sum;
    }
    __syncthreads();

    // 2. per-row max over width -> rm[24]
    if (t < H) {
        float m = act[t * W];
        #pragma unroll
        for (int w = 1; w < W; w++) m = fmaxf(m, act[t * W + w]);
        rm[t] = m;
    }
    __syncthreads();

    // 3. rank rows; compact the top-RH (dropped) row indices
    if (t < H) {
        const float mt = rm[t];
        int cnt = 0;
        #pragma unroll
        for (int j = 0; j < H; j++) {
            float mj = rm[j];
            if (mj > mt || (mj == mt && j > t)) cnt++;
        }
        if (cnt < RH) dIdx[cnt] = t;   // unique slot, no atomics needed
    }
    __syncthreads();

    // 4. zero-patch: 1536 f4 stores over 6 iterations (last one partial)
    f4* __restrict__ o4 = (f4*)out + (size_t)(b * C + chunk * CCH) * S4;
    const f4 z = {0.f, 0.f, 0.f, 0.f};
    #pragma unroll
    for (int k = 0; k < 6; ++k) {
        const int idx = t + 288 * k;           // 0..1727, guard at 1536
        if (idx < CCH * RH * W4) {
            const int c   = idx / (RH * W4);   // channel within chunk
            const int rem = idx - c * (RH * W4);
            const int i   = rem / W4;          // dropped-row slot
            const int j   = rem - i * W4;      // f4 within row
            o4[c * S4 + dIdx[i] * W4 + j] = z;
        }
    }
}

extern "C" void kernel_launch(void* const* d_in, const int* in_sizes, int n_in,
                              void* d_out, int out_size, void* d_ws, size_t ws_size,
                              hipStream_t stream) {
    const float* x   = (const float*)d_in[0];
    float*       out = (float*)d_out;

    // ws layout: [ partials: B*NCH*S floats = 2.36 MB ]
    float* part = (float*)d_ws;

    k_energy_copy<<<dim3(NCH, B), 288, 0, stream>>>(x, out, part);
    k_select_zero<<<dim3(NCH, B), 288, 0, stream>>>(part, out);
}